// Round 7
// baseline (677.414 us; speedup 1.0000x reference)
//
#include <hip/hip_runtime.h>
#include <hip/hip_bf16.h>
#include <math.h>
#include <stdint.h>

// ---------------------------------------------------------------------------
// SceneSegmenter Round 11: barrier-free attention round.
//  - attn_split3: NO LDS, NO barriers. K fragments load directly from bf16
//    proj (token-major = fragment order); V fragments load directly from
//    Vtb (packed in PV fragment order by vpack). Waves fully independent;
//    loads overlap softmax/MFMA freely (no barrier fences).
//  - Everything else identical to the passing Round-10 kernel.
// Layouts: token-major activations (S, B, D) flat, row = s*8+b.
// ---------------------------------------------------------------------------

#define DEV static __device__ __forceinline__

typedef __attribute__((ext_vector_type(8))) short bf16x8;   // 8 bf16 (4 VGPRs)
typedef __attribute__((ext_vector_type(4))) float f32x4;    // MFMA C/D

DEV uint32_t pk2bf(float a, float b) {       // packed fp32x2 -> bf16x2 (RNE)
  __hip_bfloat162 h = __float22bfloat162_rn(make_float2(a, b));
  return *(uint32_t*)&h;
}
DEV uint2 cvt4(float4 f) {                   // 4 fp32 -> 4 bf16
  return make_uint2(pk2bf(f.x, f.y), pk2bf(f.z, f.w));
}
DEV uint16_t bf1(float a) { return (uint16_t)(pk2bf(a, 0.f) & 0xffffu); }
DEV float frombf(uint16_t h) {
  union { uint32_t u; float f; } v; v.u = ((uint32_t)h) << 16; return v.f;
}

#define WAIT_VM0()  __asm__ volatile("s_waitcnt vmcnt(0)" ::: "memory")
#define WAIT_LGKM0() __asm__ volatile("s_waitcnt lgkmcnt(0)" ::: "memory")
#define RAW_BARRIER() __builtin_amdgcn_s_barrier()

// Weight-pack offsets (halves) inside WB
#define OFF_PW      0u
#define OFF_CW      262144u
#define OFF_AW      327680u
#define OFF_UW      393216u
#define OFF_EW      458752u
#define OFF_LAWIN   524288u
#define OFF_LAWOUT  573440u
#define OFF_BEW     589824u
#define OFF_BAWIN   622592u
#define OFF_BAWOUT  671744u
#define OFF_END     688128u

struct WPtrs { const float* p[10]; };

// ---------------------------------------------------------------------------
// pack_weights: concatenated fp32 weights -> bf16 WB. 672 blocks x 256 thr.
// ---------------------------------------------------------------------------
__global__ __launch_bounds__(256) void pack_weights(WPtrs wp, uint16_t* __restrict__ WB)
{
  const uint32_t off[11] = {OFF_PW, OFF_CW, OFF_AW, OFF_UW, OFF_EW, OFF_LAWIN,
                            OFF_LAWOUT, OFF_BEW, OFF_BAWIN, OFF_BAWOUT, OFF_END};
  uint32_t h = (blockIdx.x * 256u + threadIdx.x) * 4u;
  if (h >= OFF_END) return;
  int s = 0;
  while (h >= off[s + 1]) ++s;
  float4 f = *(const float4*)(wp.p[s] + (h - off[s]));
  *(uint2*)(WB + h) = cvt4(f);
}

// ---------------------------------------------------------------------------
// Templated bf16 MFMA GEMM, BM=64 x BN=128, BK=64, 256 thr = 4 waves.
// Raw-barrier async k-loop: loads for step k+1 fly under compute of step k.
// ---------------------------------------------------------------------------
template<bool ABF, bool OBF, bool RELU, bool REMAP>
__global__ __launch_bounds__(256) void gemm64(
    const void* __restrict__ Ap, int lda,
    const uint16_t* __restrict__ Wb,
    const float* __restrict__ bias,
    void* __restrict__ Cp, int ldc,
    int M, int K)
{
  __shared__ __align__(16) uint16_t As[64 * 72];
  __shared__ __align__(16) uint16_t Ws[128 * 72];

  const int t  = threadIdx.x;
  const int m0 = blockIdx.x * 64;
  const int n0 = blockIdx.y * 128;
  const int w  = t >> 6, l = t & 63;
  const int ln = l & 15, qd = l >> 4;

  f32x4 acc[4][2];
#pragma unroll
  for (int i = 0; i < 4; ++i) { acc[i][0] = (f32x4){0,0,0,0}; acc[i][1] = (f32x4){0,0,0,0}; }

  const int rr = t >> 4;          // fp32-A path: 16 rows
  const int cl = (t & 15) * 4;
  const int r8 = t >> 3;          // bf16 paths: 32 rows
  const int c8 = (t & 7) * 8;     // half col (16B)

  float4 a32[4];
  bf16x8 a16[2];
  bf16x8 wreg[4];

  auto loadA = [&](int k0) {
    if (ABF) {
      const uint16_t* A = (const uint16_t*)Ap;
#pragma unroll
      for (int i = 0; i < 2; ++i) {
        int m = m0 + r8 + 32 * i;
        int mc = m < M ? m : M - 1;
        a16[i] = *(const bf16x8*)(A + (size_t)mc * lda + k0 + c8);
      }
    } else {
      const float* A = (const float*)Ap;
#pragma unroll
      for (int i = 0; i < 4; ++i) {
        int m = m0 + rr + 16 * i;
        int mc = m < M ? m : M - 1;
        a32[i] = *(const float4*)(A + (size_t)mc * lda + k0 + cl);
      }
    }
#pragma unroll
    for (int i = 0; i < 4; ++i) {
      int n = r8 + 32 * i;
      wreg[i] = *(const bf16x8*)(Wb + (size_t)(n0 + n) * K + k0 + c8);
    }
  };
  auto writeLDS = [&]() {
    if (ABF) {
#pragma unroll
      for (int i = 0; i < 2; ++i)
        *(bf16x8*)(As + (size_t)(r8 + 32 * i) * 72 + c8) = a16[i];
    } else {
#pragma unroll
      for (int i = 0; i < 4; ++i)
        *(uint2*)(As + (size_t)(rr + 16 * i) * 72 + cl) = cvt4(a32[i]);
    }
#pragma unroll
    for (int i = 0; i < 4; ++i)
      *(bf16x8*)(Ws + (size_t)(r8 + 32 * i) * 72 + c8) = wreg[i];
  };

  loadA(0);
  for (int k0 = 0; k0 < K; k0 += 64) {
    WAIT_VM0();                 // step-k regs arrived
    writeLDS();
    WAIT_LGKM0();               // my LDS writes done
    RAW_BARRIER();              // all waves' writes visible
    if (k0 + 64 < K) loadA(k0 + 64);   // in flight under compute
#pragma unroll
    for (int ks = 0; ks < 2; ++ks) {
      bf16x8 af[4], bfr[2];
#pragma unroll
      for (int mf = 0; mf < 4; ++mf)
        af[mf] = *(const bf16x8*)(As + (size_t)(mf * 16 + ln) * 72 + ks * 32 + qd * 8);
#pragma unroll
      for (int nf = 0; nf < 2; ++nf)
        bfr[nf] = *(const bf16x8*)(Ws + (size_t)(w * 32 + nf * 16 + ln) * 72 + ks * 32 + qd * 8);
#pragma unroll
      for (int mf = 0; mf < 4; ++mf)
#pragma unroll
        for (int nf = 0; nf < 2; ++nf)
          acc[mf][nf] = __builtin_amdgcn_mfma_f32_16x16x32_bf16(af[mf], bfr[nf], acc[mf][nf], 0, 0, 0);
    }
    RAW_BARRIER();              // all waves done reading LDS
  }

#pragma unroll
  for (int mf = 0; mf < 4; ++mf) {
#pragma unroll
    for (int r = 0; r < 4; ++r) {
      int m = m0 + mf * 16 + qd * 4 + r;
      if (m < M) {
        size_t ro = REMAP ? (size_t)((m & 2047) * 8 + (m >> 11)) : (size_t)m;
#pragma unroll
        for (int nf = 0; nf < 2; ++nf) {
          int n = n0 + w * 32 + nf * 16 + ln;
          float v = acc[mf][nf][r] + bias[n];
          if (RELU) v = fmaxf(v, 0.f);
          if (OBF) ((uint16_t*)Cp)[ro * (size_t)ldc + n] = bf1(v);
          else     ((float*)Cp)[ro * (size_t)ldc + n] = v;
        }
      }
    }
  }
}

// ---------------------------------------------------------------------------
// Fused 4-segment feats GEMM (A = x fp32, W bf16), raw-barrier async k-loop.
// ---------------------------------------------------------------------------
__global__ __launch_bounds__(256) void gemm_feats64(
    const float* __restrict__ x, const uint16_t* __restrict__ WB,
    const float* __restrict__ pb, const float* __restrict__ cb,
    const float* __restrict__ ab, const float* __restrict__ ub,
    uint16_t* __restrict__ feats)
{
  __shared__ __align__(16) uint16_t As[64 * 72];
  __shared__ __align__(16) uint16_t Ws[128 * 72];

  const int seg = blockIdx.y;
  const uint16_t* Wb; const float* bias; int kbase, Kseg;
  if (seg == 0)      { Wb = WB + OFF_PW; bias = pb; kbase = 0;    Kseg = 2048; }
  else if (seg == 1) { Wb = WB + OFF_CW; bias = cb; kbase = 2048; Kseg = 512; }
  else if (seg == 2) { Wb = WB + OFF_AW; bias = ab; kbase = 2560; Kseg = 512; }
  else               { Wb = WB + OFF_UW; bias = ub; kbase = 3072; Kseg = 512; }

  const int t  = threadIdx.x;
  const int m0 = blockIdx.x * 64;
  const int w  = t >> 6, l = t & 63;
  const int ln = l & 15, qd = l >> 4;

  f32x4 acc[4][2];
#pragma unroll
  for (int i = 0; i < 4; ++i) { acc[i][0] = (f32x4){0,0,0,0}; acc[i][1] = (f32x4){0,0,0,0}; }

  const int rr = t >> 4;
  const int cl = (t & 15) * 4;
  const int r8 = t >> 3;
  const int c8 = (t & 7) * 8;

  float4 a32[4];
  bf16x8 wreg[4];

  auto loadA = [&](int k0) {
#pragma unroll
    for (int i = 0; i < 4; ++i) {
      int m = m0 + rr + 16 * i;
      a32[i] = *(const float4*)(x + (size_t)m * 3584 + kbase + k0 + cl);
    }
#pragma unroll
    for (int i = 0; i < 4; ++i) {
      int n = r8 + 32 * i;
      wreg[i] = *(const bf16x8*)(Wb + (size_t)n * Kseg + k0 + c8);
    }
  };

  loadA(0);
  for (int k0 = 0; k0 < Kseg; k0 += 64) {
    WAIT_VM0();
#pragma unroll
    for (int i = 0; i < 4; ++i)
      *(uint2*)(As + (size_t)(rr + 16 * i) * 72 + cl) = cvt4(a32[i]);
#pragma unroll
    for (int i = 0; i < 4; ++i)
      *(bf16x8*)(Ws + (size_t)(r8 + 32 * i) * 72 + c8) = wreg[i];
    WAIT_LGKM0();
    RAW_BARRIER();
    if (k0 + 64 < Kseg) loadA(k0 + 64);
#pragma unroll
    for (int ks = 0; ks < 2; ++ks) {
      bf16x8 af[4], bfr[2];
#pragma unroll
      for (int mf = 0; mf < 4; ++mf)
        af[mf] = *(const bf16x8*)(As + (size_t)(mf * 16 + ln) * 72 + ks * 32 + qd * 8);
#pragma unroll
      for (int nf = 0; nf < 2; ++nf)
        bfr[nf] = *(const bf16x8*)(Ws + (size_t)(w * 32 + nf * 16 + ln) * 72 + ks * 32 + qd * 8);
#pragma unroll
      for (int mf = 0; mf < 4; ++mf)
#pragma unroll
        for (int nf = 0; nf < 2; ++nf)
          acc[mf][nf] = __builtin_amdgcn_mfma_f32_16x16x32_bf16(af[mf], bfr[nf], acc[mf][nf], 0, 0, 0);
    }
    RAW_BARRIER();
  }

#pragma unroll
  for (int mf = 0; mf < 4; ++mf) {
#pragma unroll
    for (int r = 0; r < 4; ++r) {
      int m = m0 + mf * 16 + qd * 4 + r;
#pragma unroll
      for (int nf = 0; nf < 2; ++nf) {
        int n = w * 32 + nf * 16 + ln;
        float v = fmaxf(acc[mf][nf][r] + bias[n], 0.f);
        feats[(size_t)m * 512 + seg * 128 + n] = bf1(v);
      }
    }
  }
}

// ---------------------------------------------------------------------------
// becat GEMM with fused cumsum chunk-offset (p3) — unchanged structure.
// ---------------------------------------------------------------------------
__global__ __launch_bounds__(256) void gemm_becat64(
    const float* __restrict__ csum, const float* __restrict__ part,
    const uint16_t* __restrict__ Wb, const float* __restrict__ bias,
    uint16_t* __restrict__ C)
{
  __shared__ __align__(16) uint16_t As[64 * 72];
  __shared__ __align__(16) uint16_t Ws[128 * 72];

  const int M = 16376, K = 256;
  const int t  = threadIdx.x;
  const int m0 = blockIdx.x * 64;
  const int w  = t >> 6, l = t & 63;
  const int ln = l & 15, qd = l >> 4;

  f32x4 acc[4][2];
#pragma unroll
  for (int i = 0; i < 4; ++i) { acc[i][0] = (f32x4){0,0,0,0}; acc[i][1] = (f32x4){0,0,0,0}; }

  const int rr = t >> 4;
  const int cl = (t & 15) * 4;
  const int r8 = t >> 3;
  const int c8 = (t & 7) * 8;

  for (int k0 = 0; k0 < K; k0 += 64) {
    __syncthreads();
#pragma unroll
    for (int i = 0; i < 4; ++i) {
      int m = m0 + rr + 16 * i;
      int mc = m < M ? m : M - 1;
      int j = mc >> 3, bb = mc & 7;
      int kk = k0 + cl;
      float4 f;
      if (kk < 128) {
        float4 v = *(const float4*)(csum + (size_t)mc * 128 + kk);
        float4 p = *(const float4*)(part + (size_t)(bb * 64 + (j >> 5)) * 128 + kk);
        float s = 1.f / (float)(j + 1);
        f = make_float4((v.x + p.x) * s, (v.y + p.y) * s,
                        (v.z + p.z) * s, (v.w + p.w) * s);
      } else {
        int d = kk - 128;
        float4 c0 = *(const float4*)(csum + (size_t)mc * 128 + d);
        float4 p0 = *(const float4*)(part + (size_t)(bb * 64 + (j >> 5)) * 128 + d);
        float4 ct = *(const float4*)(csum + (size_t)(16376 + bb) * 128 + d);
        float4 pt = *(const float4*)(part + (size_t)(bb * 64 + 63) * 128 + d);
        float s = 1.f / (float)(2047 - j);
        f = make_float4(((ct.x + pt.x) - (c0.x + p0.x)) * s,
                        ((ct.y + pt.y) - (c0.y + p0.y)) * s,
                        ((ct.z + pt.z) - (c0.z + p0.z)) * s,
                        ((ct.w + pt.w) - (c0.w + p0.w)) * s);
      }
      *(uint2*)(As + (size_t)(rr + 16 * i) * 72 + cl) = cvt4(f);
    }
#pragma unroll
    for (int i = 0; i < 4; ++i) {
      int n = r8 + 32 * i;
      *(bf16x8*)(Ws + (size_t)n * 72 + c8) =
          *(const bf16x8*)(Wb + (size_t)n * K + k0 + c8);
    }
    __syncthreads();
#pragma unroll
    for (int ks = 0; ks < 2; ++ks) {
      bf16x8 af[4], bfr[2];
#pragma unroll
      for (int mf = 0; mf < 4; ++mf)
        af[mf] = *(const bf16x8*)(As + (size_t)(mf * 16 + ln) * 72 + ks * 32 + qd * 8);
#pragma unroll
      for (int nf = 0; nf < 2; ++nf)
        bfr[nf] = *(const bf16x8*)(Ws + (size_t)(w * 32 + nf * 16 + ln) * 72 + ks * 32 + qd * 8);
#pragma unroll
      for (int mf = 0; mf < 4; ++mf)
#pragma unroll
        for (int nf = 0; nf < 2; ++nf)
          acc[mf][nf] = __builtin_amdgcn_mfma_f32_16x16x32_bf16(af[mf], bfr[nf], acc[mf][nf], 0, 0, 0);
    }
  }

#pragma unroll
  for (int mf = 0; mf < 4; ++mf) {
#pragma unroll
    for (int r = 0; r < 4; ++r) {
      int m = m0 + mf * 16 + qd * 4 + r;
      if (m < M) {
#pragma unroll
        for (int nf = 0; nf < 2; ++nf) {
          int n = w * 32 + nf * 16 + ln;
          C[(size_t)m * 128 + n] = bf1(fmaxf(acc[mf][nf][r] + bias[n], 0.f));
        }
      }
    }
  }
}

// ---------------------------------------------------------------------------
// vpack: V third of bf16 proj -> Vtb [b][tile32][d128][key64].
// u32 slot u holds keys K,K+1, K = 32(u>>4)+16((u>>1)&1)+4((u>>2)&3)+2(u&1).
// ---------------------------------------------------------------------------
__global__ __launch_bounds__(256) void vpack(
    const uint16_t* __restrict__ proj, uint16_t* __restrict__ Vtb, int Slen)
{
  __shared__ __align__(16) uint16_t Vs[64][136];

  const int kt = blockIdx.x, b = blockIdx.y, t = threadIdx.x;
  const int sl = t >> 2, cg = (t & 3) * 32;
  const int s  = kt * 64 + sl;
  const int valid = s < Slen;
  const int sc2 = valid ? s : Slen - 1;
  const uint16_t* src = proj + ((size_t)sc2 * 8 + b) * 384 + 256 + cg;
#pragma unroll
  for (int i = 0; i < 4; ++i) {
    bf16x8 v;
    if (valid) v = *(const bf16x8*)(src + i * 8);
    else       v = (bf16x8){0,0,0,0,0,0,0,0};
    *(bf16x8*)(&Vs[sl][cg + i * 8]) = v;
  }
  __syncthreads();
  const int d = t >> 1, hh = t & 1;     // hh = ks2 half (keys 32hh..32hh+31)
  uint32_t wv[16];
#pragma unroll
  for (int i = 0; i < 16; ++i) {
    int K = 32 * hh + 16 * ((i >> 1) & 1) + 4 * ((i >> 2) & 3) + 2 * (i & 1);
    wv[i] = (uint32_t)Vs[K][d] | ((uint32_t)Vs[K + 1][d] << 16);
  }
  uint16_t* dv = Vtb + (((size_t)b * 32 + kt) * 128 + d) * 64 + hh * 32;
#pragma unroll
  for (int i = 0; i < 4; ++i)
    *(uint4*)(dv + i * 8) = *(uint4*)(&wv[i * 4]);
}

// ---------------------------------------------------------------------------
// 3-way split-K flash attention: barrier-free, LDS-free. K fragments come
// straight from bf16 proj; V fragments straight from Vtb (fragment order).
// Swapped QK^T (lane owns q=ln), in-register softmax + P repack.
// ---------------------------------------------------------------------------
__global__ __launch_bounds__(256) void attn_split3(
    const uint16_t* __restrict__ proj, const uint16_t* __restrict__ Vtb,
    float* __restrict__ Opart, float* __restrict__ ml, int Slen)
{
  const int t  = threadIdx.x;
  const int b  = blockIdx.y;
  const int q0 = blockIdx.x * 64;
  const int split = blockIdx.z;
  const int kbeg = split * 704;
  const int kend = (split == 2) ? Slen : kbeg + 704;
  const int w  = t >> 6;
  const int l  = t & 63;
  const int ln = l & 15;
  const int qd = l >> 4;
  const float scl = 0.08838834764831845f;   // 1/sqrt(128)

  bf16x8 qf[4];
  {
    int qrow = q0 + w * 16 + ln;
    int qc = qrow < Slen ? qrow : Slen - 1;
    const uint16_t* qp = proj + ((size_t)qc * 8 + b) * 384 + qd * 8;
#pragma unroll
    for (int ks = 0; ks < 4; ++ks) {
      union { bf16x8 v; uint16_t h[8]; uint32_t u[4]; } in, out;
      in.v = *(const bf16x8*)(qp + ks * 32);
#pragma unroll
      for (int j = 0; j < 4; ++j)
        out.u[j] = pk2bf(frombf(in.h[2 * j]) * scl, frombf(in.h[2 * j + 1]) * scl);
      qf[ks] = out.v;
    }
  }

  f32x4 oacc[8];
#pragma unroll
  for (int i = 0; i < 8; ++i) oacc[i] = (f32x4){0.f, 0.f, 0.f, 0.f};
  float mrow = -INFINITY;          // per-lane: q = q0 + w*16 + ln
  float lrow = 0.f;

  const int ntiles = (kend - kbeg + 63) >> 6;

  for (int kt = 0; kt < ntiles; ++kt) {
    const int key0 = kbeg + kt * 64;

    // QK^T swapped: K fragments direct from proj. lane holds
    // S[key = nf*16 + qd*4 + r][q = ln].
    float sc[4][4];
    __builtin_amdgcn_s_setprio(1);
#pragma unroll
    for (int nf = 0; nf < 4; ++nf) {
      int key = key0 + nf * 16 + ln;
      int kc = key < Slen ? key : Slen - 1;
      const uint16_t* kp = proj + ((size_t)kc * 8 + b) * 384 + 128 + qd * 8;
      f32x4 acc = (f32x4){0.f, 0.f, 0.f, 0.f};
#pragma unroll
      for (int ks = 0; ks < 4; ++ks) {
        bf16x8 kf = *(const bf16x8*)(kp + ks * 32);
        acc = __builtin_amdgcn_mfma_f32_16x16x32_bf16(kf, qf[ks], acc, 0, 0, 0);
      }
      int keyb = key0 + nf * 16 + qd * 4;
#pragma unroll
      for (int r = 0; r < 4; ++r)
        sc[nf][r] = (keyb + r < kend) ? acc[r] : -1e30f;
    }
    __builtin_amdgcn_s_setprio(0);

    // online softmax: in-lane 16-max + 2 shuffles
    float mx = sc[0][0];
#pragma unroll
    for (int nf = 0; nf < 4; ++nf)
#pragma unroll
      for (int r = 0; r < 4; ++r) mx = fmaxf(mx, sc[nf][r]);
    mx = fmaxf(mx, __shfl_xor(mx, 16));
    mx = fmaxf(mx, __shfl_xor(mx, 32));
    float mNew = fmaxf(mrow, mx);

    float ps = 0.f;
#pragma unroll
    for (int nf = 0; nf < 4; ++nf) {
      float p0 = __expf(sc[nf][0] - mNew);
      float p1 = __expf(sc[nf][1] - mNew);
      float p2 = __expf(sc[nf][2] - mNew);
      float p3 = __expf(sc[nf][3] - mNew);
      sc[nf][0] = p0; sc[nf][1] = p1; sc[nf][2] = p2; sc[nf][3] = p3;
      ps += (p0 + p1) + (p2 + p3);
    }
    ps += __shfl_xor(ps, 16);
    ps += __shfl_xor(ps, 32);

    float alpha = __expf(mrow - mNew);
    mrow = mNew;
    lrow = lrow * alpha + ps;

    // alpha for the lane's OUTPUT rows q' = qd*4 + r
    float alphaR[4];
#pragma unroll
    for (int r = 0; r < 4; ++r)
      alphaR[r] = __shfl(alpha, (l & 48) | (qd * 4 + r));
#pragma unroll
    for (int no = 0; no < 8; ++no) {
#pragma unroll
      for (int r = 0; r < 4; ++r) oacc[no][r] *= alphaR[r];
    }

    // in-register P -> PV A-fragments (order matches vpack permutation)
    union { bf16x8 v; uint32_t u[4]; } pa0, pa1;
#pragma unroll
    for (int i = 0; i < 4; ++i) {
      pa0.u[i] = pk2bf(sc[(i >> 1)][(i & 1) * 2],     sc[(i >> 1)][(i & 1) * 2 + 1]);
      pa1.u[i] = pk2bf(sc[2 + (i >> 1)][(i & 1) * 2], sc[2 + (i >> 1)][(i & 1) * 2 + 1]);
    }

    // PV: V fragments direct from Vtb (already transposed + permuted)
    const uint16_t* vbase = Vtb + (((size_t)b * 32 + 11 * split + kt) * 128) * 64;
    __builtin_amdgcn_s_setprio(1);
#pragma unroll
    for (int no = 0; no < 8; ++no) {
      bf16x8 vf = *(const bf16x8*)(vbase + (size_t)(no * 16 + ln) * 64 + qd * 8);
      oacc[no] = __builtin_amdgcn_mfma_f32_16x16x32_bf16(pa0.v, vf, oacc[no], 0, 0, 0);
    }
#pragma unroll
    for (int no = 0; no < 8; ++no) {
      bf16x8 vf = *(const bf16x8*)(vbase + (size_t)(no * 16 + ln) * 64 + 32 + qd * 8);
      oacc[no] = __builtin_amdgcn_mfma_f32_16x16x32_bf16(pa1.v, vf, oacc[no], 0, 0, 0);
    }
    __builtin_amdgcn_s_setprio(0);
  }

  // store unnormalized partials + (m, l)
#pragma unroll
  for (int r = 0; r < 4; ++r) {
    int qg = q0 + w * 16 + qd * 4 + r;
    if (qg < Slen) {
      size_t row = (size_t)qg * 8 + b;
      float* dst = Opart + ((size_t)split * 16384 + row) * 128 + ln;
#pragma unroll
      for (int no = 0; no < 8; ++no) dst[no * 16] = oacc[no][r];
    }
  }
  {
    int qg = q0 + w * 16 + ln;
    if (qd == 0 && qg < Slen) {
      size_t row = (size_t)qg * 8 + b;
      ml[((size_t)split * 16384 + row) * 2 + 0] = mrow;
      ml[((size_t)split * 16384 + row) * 2 + 1] = lrow;
    }
  }
}

// ---------------------------------------------------------------------------
// Out-proj GEMM with INLINE split-combine A-staging, raw-barrier async.
// ---------------------------------------------------------------------------
template<bool HEAD>
__global__ __launch_bounds__(256) void gemm_attc64(
    const float* __restrict__ Opart, const float* __restrict__ ml,
    const uint16_t* __restrict__ Wb,
    const float* __restrict__ bias,
    const float* __restrict__ bpW, const float* __restrict__ bpb,
    float* __restrict__ out, int M)
{
  __shared__ __align__(16) uint16_t As[64 * 72];
  __shared__ __align__(16) uint16_t Ws[128 * 72];
  __shared__ float RW[64][4];                 // w0,w1,w2,inv per row
  __shared__ float Ct[HEAD ? 64 : 1][133];

  const int K = 128;
  const int t  = threadIdx.x;
  const int m0 = blockIdx.x * 64;
  const int w  = t >> 6, l = t & 63;
  const int ln = l & 15, qd = l >> 4;

  if (t < 64) {
    int m = m0 + t;
    int mc = m < M ? m : M - 1;
    float m0v = ml[(size_t)mc * 2],                 l0 = ml[(size_t)mc * 2 + 1];
    float m1v = ml[((size_t)16384 + mc) * 2],       l1 = ml[((size_t)16384 + mc) * 2 + 1];
    float m2v = ml[((size_t)32768 + mc) * 2],       l2 = ml[((size_t)32768 + mc) * 2 + 1];
    float Mx = fmaxf(fmaxf(m0v, m1v), m2v);
    float w0 = __expf(m0v - Mx), w1 = __expf(m1v - Mx), w2 = __expf(m2v - Mx);
    RW[t][0] = w0; RW[t][1] = w1; RW[t][2] = w2;
    RW[t][3] = 1.f / (l0 * w0 + l1 * w1 + l2 * w2);
  }
  __syncthreads();      // RW visible before first (pre-barrier) A-staging

  f32x4 acc[4][2];
#pragma unroll
  for (int i = 0; i < 4; ++i) { acc[i][0] = (f32x4){0,0,0,0}; acc[i][1] = (f32x4){0,0,0,0}; }

  const int rr = t >> 4;
  const int cl = (t & 15) * 4;
  const int r8 = t >> 3;
  const int c8 = (t & 7) * 8;

  float4 ra[4], rc[4], re[4];
  bf16x8 wreg[4];

  auto loadA = [&](int k0) {
#pragma unroll
    for (int i = 0; i < 4; ++i) {
      int m = m0 + rr + 16 * i;
      int mc = m < M ? m : M - 1;
      int kk = k0 + cl;
      ra[i] = *(const float4*)(Opart + (size_t)mc * 128 + kk);
      rc[i] = *(const float4*)(Opart + ((size_t)16384 + mc) * 128 + kk);
      re[i] = *(const float4*)(Opart + ((size_t)32768 + mc) * 128 + kk);
    }
#pragma unroll
    for (int i = 0; i < 4; ++i) {
      int n = r8 + 32 * i;
      wreg[i] = *(const bf16x8*)(Wb + (size_t)n * K + k0 + c8);
    }
  };

  loadA(0);
  for (int k0 = 0; k0 < K; k0 += 64) {
    WAIT_VM0();
#pragma unroll
    for (int i = 0; i < 4; ++i) {
      int rl = rr + 16 * i;
      float w0 = RW[rl][0], w1 = RW[rl][1], w2 = RW[rl][2], inv = RW[rl][3];
      float4 f = make_float4((ra[i].x * w0 + rc[i].x * w1 + re[i].x * w2) * inv,
                             (ra[i].y * w0 + rc[i].y * w1 + re[i].y * w2) * inv,
                             (ra[i].z * w0 + rc[i].z * w1 + re[i].z * w2) * inv,
                             (ra[i].w * w0 + rc[i].w * w1 + re[i].w * w2) * inv);
      *(uint2*)(As + (size_t)rl * 72 + cl) = cvt4(f);
    }
#pragma unroll
    for (int i = 0; i < 4; ++i)
      *(bf16x8*)(Ws + (size_t)(r8 + 32 * i) * 72 + c8) = wreg[i];
    WAIT_LGKM0();
    RAW_BARRIER();
    if (k0 + 64 < K) loadA(k0 + 64);
#pragma unroll
    for (int ks = 0; ks < 2; ++ks) {
      bf16x8 af[4], bfr[2];
#pragma unroll
      for (int mf = 0; mf < 4; ++mf)
        af[mf] = *(const bf16x8*)(As + (size_t)(mf * 16 + ln) * 72 + ks * 32 + qd * 8);
#pragma unroll
      for (int nf = 0; nf < 2; ++nf)
        bfr[nf] = *(const bf16x8*)(Ws + (size_t)(w * 32 + nf * 16 + ln) * 72 + ks * 32 + qd * 8);
#pragma unroll
      for (int mf = 0; mf < 4; ++mf)
#pragma unroll
        for (int nf = 0; nf < 2; ++nf)
          acc[mf][nf] = __builtin_amdgcn_mfma_f32_16x16x32_bf16(af[mf], bfr[nf], acc[mf][nf], 0, 0, 0);
    }
    RAW_BARRIER();
  }

  if (HEAD) {
    __syncthreads();
#pragma unroll
    for (int mf = 0; mf < 4; ++mf) {
#pragma unroll
      for (int r = 0; r < 4; ++r) {
        int rowL = mf * 16 + qd * 4 + r;
#pragma unroll
        for (int nf = 0; nf < 2; ++nf) {
          int n = w * 32 + nf * 16 + ln;
          Ct[rowL][n] = acc[mf][nf][r] + bias[n];
        }
      }
    }
    __syncthreads();
    int row = t >> 2, qg = t & 3;
    int m = m0 + row;
    float p = 0.f;
#pragma unroll
    for (int j = 0; j < 32; ++j) {
      int c = qg + j * 4;
      p += Ct[row][c] * bpW[c];
    }
    p += __shfl_xor(p, 1);
    p += __shfl_xor(p, 2);
    if (qg == 0 && m < M)
      out[m] = 1.f / (1.f + __expf(-(p + bpb[0])));
  } else {
#pragma unroll
    for (int mf = 0; mf < 4; ++mf) {
#pragma unroll
      for (int r = 0; r < 4; ++r) {
        int m = m0 + mf * 16 + qd * 4 + r;
        if (m < M) {
#pragma unroll
          for (int nf = 0; nf < 2; ++nf) {
            int n = w * 32 + nf * 16 + ln;
            out[(size_t)m * 128 + n] = acc[mf][nf][r] + bias[n];
          }
        }
      }
    }
  }
}

// ---------------------------------------------------------------------------
// Cumsum over s of e (S,B,128): 64 chunks x 32 rows (512 blocks p1).
// ---------------------------------------------------------------------------
__global__ void cumsum_p1(const float* __restrict__ e, float* __restrict__ csum,
                          float* __restrict__ part)
{
  int chunk = blockIdx.x, b = blockIdx.y, d = threadIdx.x;
  float run = 0.f;
  int s0 = chunk * 32;
  for (int s = 0; s < 32; ++s) {
    size_t idx = ((size_t)(s0 + s) * 8 + b) * 128 + d;
    run += e[idx];
    csum[idx] = run;
  }
  part[(b * 64 + chunk) * 128 + d] = run;
}

__global__ void cumsum_p2(float* __restrict__ part)
{
  int b = blockIdx.x, d = threadIdx.x;
  float run = 0.f;
  for (int c = 0; c < 64; ++c) {
    float v = part[(b * 64 + c) * 128 + d];
    part[(b * 64 + c) * 128 + d] = run;
    run += v;
  }
}

// ---------------------------------------------------------------------------
extern "C" void kernel_launch(void* const* d_in, const int* in_sizes, int n_in,
                              void* d_out, int out_size, void* d_ws, size_t ws_size,
                              hipStream_t stream)
{
  const float* x       = (const float*)d_in[0];
  const float* pW      = (const float*)d_in[1];
  const float* pb      = (const float*)d_in[2];
  const float* cW      = (const float*)d_in[3];
  const float* cb      = (const float*)d_in[4];
  const float* aW      = (const float*)d_in[5];
  const float* ab      = (const float*)d_in[6];
  const float* uW      = (const float*)d_in[7];
  const float* ub      = (const float*)d_in[8];
  const float* eW      = (const float*)d_in[9];
  const float* eb      = (const float*)d_in[10];
  const float* la_win  = (const float*)d_in[11];
  const float* la_bin  = (const float*)d_in[12];
  const float* la_wout = (const float*)d_in[13];
  const float* la_bout = (const float*)d_in[14];
  const float* beW     = (const float*)d_in[15];
  const float* beb     = (const float*)d_in[16];
  const float* ba_win  = (const float*)d_in[17];
  const float* ba_bin  = (const float*)d_in[18];
  const float* ba_wout = (const float*)d_in[19];
  const float* ba_bout = (const float*)d_in[20];
  const float* bpW     = (const float*)d_in[21];
  const float* bpb     = (const float*)d_in[22];

  float* ws   = (float*)d_ws;
  float* outF = (float*)d_out;

  uint16_t* WB  = (uint16_t*)ws;
  float* base   = ws + 344064;
  uint16_t* featsB = (uint16_t*)base;
  float* csumB  = base;
  float* partB  = base + 2097152;
  uint16_t* eB  = (uint16_t*)(base + 4194304);   // e0 / b0
  uint16_t* projB = (uint16_t*)(base + 5242880);
  uint16_t* VtbB  = (uint16_t*)(base + 8388608);
  float* OpartB = base + 9437184;
  float* mlB    = base + 15728640;

  // 0. weights -> bf16
  WPtrs wp;
  wp.p[0] = pW; wp.p[1] = cW; wp.p[2] = aW; wp.p[3] = uW; wp.p[4] = eW;
  wp.p[5] = la_win; wp.p[6] = la_wout; wp.p[7] = beW; wp.p[8] = ba_win; wp.p[9] = ba_wout;
  pack_weights<<<dim3(672), 256, 0, stream>>>(wp, WB);

  // 1. feats = relu(segment linears) -> bf16
  gemm_feats64<<<dim3(256, 4), 256, 0, stream>>>(x, WB, pb, cb, ab, ub, featsB);
  // 2. e0 = relu(feats @ eW^T + eb) -> bf16, remapped (B,S)->(S,B)
  gemm64<true, true, true, true><<<dim3(256, 1), 256, 0, stream>>>(
      featsB, 512, WB + OFF_EW, eb, eB, 128, 16384, 512);
  // 3. proj1 = e0 @ la_win^T + la_bin -> bf16
  gemm64<true, true, false, false><<<dim3(256, 3), 256, 0, stream>>>(
      eB, 128, WB + OFF_LAWIN, la_bin, projB, 384, 16384, 128);
  // 4. V pack + 3-split flash (barrier-free)
  vpack<<<dim3(32, 8), 256, 0, stream>>>(projB, VtbB, 2048);
  attn_split3<<<dim3(32, 8, 3), 256, 0, stream>>>(projB, VtbB, OpartB, mlB, 2048);
  // 5. e = combine(att1) @ la_wout^T + la_bout -> d_out (fp32), combine inlined
  gemm_attc64<false><<<dim3(256), 256, 0, stream>>>(
      OpartB, mlB, WB + OFF_LAWOUT, la_bout, nullptr, nullptr, outF, 16384);
  // 6-7. csum (local prefixes + chunk offsets; p3 fused into becat)
  cumsum_p1<<<dim3(64, 8), 128, 0, stream>>>(outF, csumB, partB);
  cumsum_p2<<<dim3(8), 128, 0, stream>>>(partB);
  // 8. b0 = relu(cat(left,right) @ beW^T + beb) -> bf16
  gemm_becat64<<<dim3(256), 256, 0, stream>>>(csumB, partB, WB + OFF_BEW, beb, eB);
  // 9. proj2
  gemm64<true, true, false, false><<<dim3(256, 3), 256, 0, stream>>>(
      eB, 128, WB + OFF_BAWIN, ba_bin, projB, 384, 16376, 128);
  // 10. V pack + att2 (Slen = 2047)
  vpack<<<dim3(32, 8), 256, 0, stream>>>(projB, VtbB, 2047);
  attn_split3<<<dim3(32, 8, 3), 256, 0, stream>>>(projB, VtbB, OpartB, mlB, 2047);
  // 11. bout GEMM: combine inlined + fused sigmoid head -> d_out tail
  gemm_attc64<true><<<dim3(256), 256, 0, stream>>>(
      OpartB, mlB, WB + OFF_BAWOUT, ba_bout, bpW, bpb, outF + 2097152, 16376);
}

// Round 8
// 509.429 us; speedup vs baseline: 1.3298x; 1.3298x over previous
//
#include <hip/hip_runtime.h>
#include <hip/hip_bf16.h>
#include <math.h>
#include <stdint.h>

// ---------------------------------------------------------------------------
// SceneSegmenter Round 12: revert R11 (fragment-direct attn regressed 160us);
// base = R10 (517us). Change: attention QBLK 64->128, 512 thr (8 waves),
// 4 splits x 512 keys -> 16 waves/CU, per-thread staging halved, K/V
// re-stage traffic halved. Combine (inlined in attc) now merges 4 partials.
// Layouts: token-major activations (S, B, D) flat, row = s*8+b.
// ---------------------------------------------------------------------------

#define DEV static __device__ __forceinline__

typedef __attribute__((ext_vector_type(8))) short bf16x8;   // 8 bf16 (4 VGPRs)
typedef __attribute__((ext_vector_type(4))) float f32x4;    // MFMA C/D

DEV uint32_t pk2bf(float a, float b) {       // packed fp32x2 -> bf16x2 (RNE)
  __hip_bfloat162 h = __float22bfloat162_rn(make_float2(a, b));
  return *(uint32_t*)&h;
}
DEV uint2 cvt4(float4 f) {                   // 4 fp32 -> 4 bf16
  return make_uint2(pk2bf(f.x, f.y), pk2bf(f.z, f.w));
}
DEV uint16_t bf1(float a) { return (uint16_t)(pk2bf(a, 0.f) & 0xffffu); }
DEV float frombf(uint16_t h) {
  union { uint32_t u; float f; } v; v.u = ((uint32_t)h) << 16; return v.f;
}

#define WAIT_VM0()  __asm__ volatile("s_waitcnt vmcnt(0)" ::: "memory")
#define WAIT_LGKM0() __asm__ volatile("s_waitcnt lgkmcnt(0)" ::: "memory")
#define RAW_BARRIER() __builtin_amdgcn_s_barrier()

// Weight-pack offsets (halves) inside WB
#define OFF_PW      0u
#define OFF_CW      262144u
#define OFF_AW      327680u
#define OFF_UW      393216u
#define OFF_EW      458752u
#define OFF_LAWIN   524288u
#define OFF_LAWOUT  573440u
#define OFF_BEW     589824u
#define OFF_BAWIN   622592u
#define OFF_BAWOUT  671744u
#define OFF_END     688128u

struct WPtrs { const float* p[10]; };

// ---------------------------------------------------------------------------
// pack_weights: concatenated fp32 weights -> bf16 WB. 672 blocks x 256 thr.
// ---------------------------------------------------------------------------
__global__ __launch_bounds__(256) void pack_weights(WPtrs wp, uint16_t* __restrict__ WB)
{
  const uint32_t off[11] = {OFF_PW, OFF_CW, OFF_AW, OFF_UW, OFF_EW, OFF_LAWIN,
                            OFF_LAWOUT, OFF_BEW, OFF_BAWIN, OFF_BAWOUT, OFF_END};
  uint32_t h = (blockIdx.x * 256u + threadIdx.x) * 4u;
  if (h >= OFF_END) return;
  int s = 0;
  while (h >= off[s + 1]) ++s;
  float4 f = *(const float4*)(wp.p[s] + (h - off[s]));
  *(uint2*)(WB + h) = cvt4(f);
}

// ---------------------------------------------------------------------------
// Templated bf16 MFMA GEMM, BM=64 x BN=128, BK=64, 256 thr = 4 waves.
// Raw-barrier async k-loop (R10, passing).
// ---------------------------------------------------------------------------
template<bool ABF, bool OBF, bool RELU, bool REMAP>
__global__ __launch_bounds__(256) void gemm64(
    const void* __restrict__ Ap, int lda,
    const uint16_t* __restrict__ Wb,
    const float* __restrict__ bias,
    void* __restrict__ Cp, int ldc,
    int M, int K)
{
  __shared__ __align__(16) uint16_t As[64 * 72];
  __shared__ __align__(16) uint16_t Ws[128 * 72];

  const int t  = threadIdx.x;
  const int m0 = blockIdx.x * 64;
  const int n0 = blockIdx.y * 128;
  const int w  = t >> 6, l = t & 63;
  const int ln = l & 15, qd = l >> 4;

  f32x4 acc[4][2];
#pragma unroll
  for (int i = 0; i < 4; ++i) { acc[i][0] = (f32x4){0,0,0,0}; acc[i][1] = (f32x4){0,0,0,0}; }

  const int rr = t >> 4;          // fp32-A path: 16 rows
  const int cl = (t & 15) * 4;
  const int r8 = t >> 3;          // bf16 paths: 32 rows
  const int c8 = (t & 7) * 8;     // half col (16B)

  float4 a32[4];
  bf16x8 a16[2];
  bf16x8 wreg[4];

  auto loadA = [&](int k0) {
    if (ABF) {
      const uint16_t* A = (const uint16_t*)Ap;
#pragma unroll
      for (int i = 0; i < 2; ++i) {
        int m = m0 + r8 + 32 * i;
        int mc = m < M ? m : M - 1;
        a16[i] = *(const bf16x8*)(A + (size_t)mc * lda + k0 + c8);
      }
    } else {
      const float* A = (const float*)Ap;
#pragma unroll
      for (int i = 0; i < 4; ++i) {
        int m = m0 + rr + 16 * i;
        int mc = m < M ? m : M - 1;
        a32[i] = *(const float4*)(A + (size_t)mc * lda + k0 + cl);
      }
    }
#pragma unroll
    for (int i = 0; i < 4; ++i) {
      int n = r8 + 32 * i;
      wreg[i] = *(const bf16x8*)(Wb + (size_t)(n0 + n) * K + k0 + c8);
    }
  };
  auto writeLDS = [&]() {
    if (ABF) {
#pragma unroll
      for (int i = 0; i < 2; ++i)
        *(bf16x8*)(As + (size_t)(r8 + 32 * i) * 72 + c8) = a16[i];
    } else {
#pragma unroll
      for (int i = 0; i < 4; ++i)
        *(uint2*)(As + (size_t)(rr + 16 * i) * 72 + cl) = cvt4(a32[i]);
    }
#pragma unroll
    for (int i = 0; i < 4; ++i)
      *(bf16x8*)(Ws + (size_t)(r8 + 32 * i) * 72 + c8) = wreg[i];
  };

  loadA(0);
  for (int k0 = 0; k0 < K; k0 += 64) {
    WAIT_VM0();                 // step-k regs arrived
    writeLDS();
    WAIT_LGKM0();               // my LDS writes done
    RAW_BARRIER();              // all waves' writes visible
    if (k0 + 64 < K) loadA(k0 + 64);   // in flight under compute
#pragma unroll
    for (int ks = 0; ks < 2; ++ks) {
      bf16x8 af[4], bfr[2];
#pragma unroll
      for (int mf = 0; mf < 4; ++mf)
        af[mf] = *(const bf16x8*)(As + (size_t)(mf * 16 + ln) * 72 + ks * 32 + qd * 8);
#pragma unroll
      for (int nf = 0; nf < 2; ++nf)
        bfr[nf] = *(const bf16x8*)(Ws + (size_t)(w * 32 + nf * 16 + ln) * 72 + ks * 32 + qd * 8);
#pragma unroll
      for (int mf = 0; mf < 4; ++mf)
#pragma unroll
        for (int nf = 0; nf < 2; ++nf)
          acc[mf][nf] = __builtin_amdgcn_mfma_f32_16x16x32_bf16(af[mf], bfr[nf], acc[mf][nf], 0, 0, 0);
    }
    RAW_BARRIER();              // all waves done reading LDS
  }

#pragma unroll
  for (int mf = 0; mf < 4; ++mf) {
#pragma unroll
    for (int r = 0; r < 4; ++r) {
      int m = m0 + mf * 16 + qd * 4 + r;
      if (m < M) {
        size_t ro = REMAP ? (size_t)((m & 2047) * 8 + (m >> 11)) : (size_t)m;
#pragma unroll
        for (int nf = 0; nf < 2; ++nf) {
          int n = n0 + w * 32 + nf * 16 + ln;
          float v = acc[mf][nf][r] + bias[n];
          if (RELU) v = fmaxf(v, 0.f);
          if (OBF) ((uint16_t*)Cp)[ro * (size_t)ldc + n] = bf1(v);
          else     ((float*)Cp)[ro * (size_t)ldc + n] = v;
        }
      }
    }
  }
}

// ---------------------------------------------------------------------------
// Fused 4-segment feats GEMM (A = x fp32, W bf16), raw-barrier async k-loop.
// ---------------------------------------------------------------------------
__global__ __launch_bounds__(256) void gemm_feats64(
    const float* __restrict__ x, const uint16_t* __restrict__ WB,
    const float* __restrict__ pb, const float* __restrict__ cb,
    const float* __restrict__ ab, const float* __restrict__ ub,
    uint16_t* __restrict__ feats)
{
  __shared__ __align__(16) uint16_t As[64 * 72];
  __shared__ __align__(16) uint16_t Ws[128 * 72];

  const int seg = blockIdx.y;
  const uint16_t* Wb; const float* bias; int kbase, Kseg;
  if (seg == 0)      { Wb = WB + OFF_PW; bias = pb; kbase = 0;    Kseg = 2048; }
  else if (seg == 1) { Wb = WB + OFF_CW; bias = cb; kbase = 2048; Kseg = 512; }
  else if (seg == 2) { Wb = WB + OFF_AW; bias = ab; kbase = 2560; Kseg = 512; }
  else               { Wb = WB + OFF_UW; bias = ub; kbase = 3072; Kseg = 512; }

  const int t  = threadIdx.x;
  const int m0 = blockIdx.x * 64;
  const int w  = t >> 6, l = t & 63;
  const int ln = l & 15, qd = l >> 4;

  f32x4 acc[4][2];
#pragma unroll
  for (int i = 0; i < 4; ++i) { acc[i][0] = (f32x4){0,0,0,0}; acc[i][1] = (f32x4){0,0,0,0}; }

  const int rr = t >> 4;
  const int cl = (t & 15) * 4;
  const int r8 = t >> 3;
  const int c8 = (t & 7) * 8;

  float4 a32[4];
  bf16x8 wreg[4];

  auto loadA = [&](int k0) {
#pragma unroll
    for (int i = 0; i < 4; ++i) {
      int m = m0 + rr + 16 * i;
      a32[i] = *(const float4*)(x + (size_t)m * 3584 + kbase + k0 + cl);
    }
#pragma unroll
    for (int i = 0; i < 4; ++i) {
      int n = r8 + 32 * i;
      wreg[i] = *(const bf16x8*)(Wb + (size_t)n * Kseg + k0 + c8);
    }
  };

  loadA(0);
  for (int k0 = 0; k0 < Kseg; k0 += 64) {
    WAIT_VM0();
#pragma unroll
    for (int i = 0; i < 4; ++i)
      *(uint2*)(As + (size_t)(rr + 16 * i) * 72 + cl) = cvt4(a32[i]);
#pragma unroll
    for (int i = 0; i < 4; ++i)
      *(bf16x8*)(Ws + (size_t)(r8 + 32 * i) * 72 + c8) = wreg[i];
    WAIT_LGKM0();
    RAW_BARRIER();
    if (k0 + 64 < Kseg) loadA(k0 + 64);
#pragma unroll
    for (int ks = 0; ks < 2; ++ks) {
      bf16x8 af[4], bfr[2];
#pragma unroll
      for (int mf = 0; mf < 4; ++mf)
        af[mf] = *(const bf16x8*)(As + (size_t)(mf * 16 + ln) * 72 + ks * 32 + qd * 8);
#pragma unroll
      for (int nf = 0; nf < 2; ++nf)
        bfr[nf] = *(const bf16x8*)(Ws + (size_t)(w * 32 + nf * 16 + ln) * 72 + ks * 32 + qd * 8);
#pragma unroll
      for (int mf = 0; mf < 4; ++mf)
#pragma unroll
        for (int nf = 0; nf < 2; ++nf)
          acc[mf][nf] = __builtin_amdgcn_mfma_f32_16x16x32_bf16(af[mf], bfr[nf], acc[mf][nf], 0, 0, 0);
    }
    RAW_BARRIER();
  }

#pragma unroll
  for (int mf = 0; mf < 4; ++mf) {
#pragma unroll
    for (int r = 0; r < 4; ++r) {
      int m = m0 + mf * 16 + qd * 4 + r;
#pragma unroll
      for (int nf = 0; nf < 2; ++nf) {
        int n = w * 32 + nf * 16 + ln;
        float v = fmaxf(acc[mf][nf][r] + bias[n], 0.f);
        feats[(size_t)m * 512 + seg * 128 + n] = bf1(v);
      }
    }
  }
}

// ---------------------------------------------------------------------------
// becat GEMM with fused cumsum chunk-offset (p3) — unchanged structure.
// ---------------------------------------------------------------------------
__global__ __launch_bounds__(256) void gemm_becat64(
    const float* __restrict__ csum, const float* __restrict__ part,
    const uint16_t* __restrict__ Wb, const float* __restrict__ bias,
    uint16_t* __restrict__ C)
{
  __shared__ __align__(16) uint16_t As[64 * 72];
  __shared__ __align__(16) uint16_t Ws[128 * 72];

  const int M = 16376, K = 256;
  const int t  = threadIdx.x;
  const int m0 = blockIdx.x * 64;
  const int w  = t >> 6, l = t & 63;
  const int ln = l & 15, qd = l >> 4;

  f32x4 acc[4][2];
#pragma unroll
  for (int i = 0; i < 4; ++i) { acc[i][0] = (f32x4){0,0,0,0}; acc[i][1] = (f32x4){0,0,0,0}; }

  const int rr = t >> 4;
  const int cl = (t & 15) * 4;
  const int r8 = t >> 3;
  const int c8 = (t & 7) * 8;

  for (int k0 = 0; k0 < K; k0 += 64) {
    __syncthreads();
#pragma unroll
    for (int i = 0; i < 4; ++i) {
      int m = m0 + rr + 16 * i;
      int mc = m < M ? m : M - 1;
      int j = mc >> 3, bb = mc & 7;
      int kk = k0 + cl;
      float4 f;
      if (kk < 128) {
        float4 v = *(const float4*)(csum + (size_t)mc * 128 + kk);
        float4 p = *(const float4*)(part + (size_t)(bb * 64 + (j >> 5)) * 128 + kk);
        float s = 1.f / (float)(j + 1);
        f = make_float4((v.x + p.x) * s, (v.y + p.y) * s,
                        (v.z + p.z) * s, (v.w + p.w) * s);
      } else {
        int d = kk - 128;
        float4 c0 = *(const float4*)(csum + (size_t)mc * 128 + d);
        float4 p0 = *(const float4*)(part + (size_t)(bb * 64 + (j >> 5)) * 128 + d);
        float4 ct = *(const float4*)(csum + (size_t)(16376 + bb) * 128 + d);
        float4 pt = *(const float4*)(part + (size_t)(bb * 64 + 63) * 128 + d);
        float s = 1.f / (float)(2047 - j);
        f = make_float4(((ct.x + pt.x) - (c0.x + p0.x)) * s,
                        ((ct.y + pt.y) - (c0.y + p0.y)) * s,
                        ((ct.z + pt.z) - (c0.z + p0.z)) * s,
                        ((ct.w + pt.w) - (c0.w + p0.w)) * s);
      }
      *(uint2*)(As + (size_t)(rr + 16 * i) * 72 + cl) = cvt4(f);
    }
#pragma unroll
    for (int i = 0; i < 4; ++i) {
      int n = r8 + 32 * i;
      *(bf16x8*)(Ws + (size_t)n * 72 + c8) =
          *(const bf16x8*)(Wb + (size_t)n * K + k0 + c8);
    }
    __syncthreads();
#pragma unroll
    for (int ks = 0; ks < 2; ++ks) {
      bf16x8 af[4], bfr[2];
#pragma unroll
      for (int mf = 0; mf < 4; ++mf)
        af[mf] = *(const bf16x8*)(As + (size_t)(mf * 16 + ln) * 72 + ks * 32 + qd * 8);
#pragma unroll
      for (int nf = 0; nf < 2; ++nf)
        bfr[nf] = *(const bf16x8*)(Ws + (size_t)(w * 32 + nf * 16 + ln) * 72 + ks * 32 + qd * 8);
#pragma unroll
      for (int mf = 0; mf < 4; ++mf)
#pragma unroll
        for (int nf = 0; nf < 2; ++nf)
          acc[mf][nf] = __builtin_amdgcn_mfma_f32_16x16x32_bf16(af[mf], bfr[nf], acc[mf][nf], 0, 0, 0);
    }
  }

#pragma unroll
  for (int mf = 0; mf < 4; ++mf) {
#pragma unroll
    for (int r = 0; r < 4; ++r) {
      int m = m0 + mf * 16 + qd * 4 + r;
      if (m < M) {
#pragma unroll
        for (int nf = 0; nf < 2; ++nf) {
          int n = w * 32 + nf * 16 + ln;
          C[(size_t)m * 128 + n] = bf1(fmaxf(acc[mf][nf][r] + bias[n], 0.f));
        }
      }
    }
  }
}

// ---------------------------------------------------------------------------
// vpack: V third of bf16 proj -> Vtb [b][tile32][d128][key64].
// u32 slot u holds keys K,K+1, K = 32(u>>4)+16((u>>1)&1)+4((u>>2)&3)+2(u&1).
// ---------------------------------------------------------------------------
__global__ __launch_bounds__(256) void vpack(
    const uint16_t* __restrict__ proj, uint16_t* __restrict__ Vtb, int Slen)
{
  __shared__ __align__(16) uint16_t Vs[64][136];

  const int kt = blockIdx.x, b = blockIdx.y, t = threadIdx.x;
  const int sl = t >> 2, cg = (t & 3) * 32;
  const int s  = kt * 64 + sl;
  const int valid = s < Slen;
  const int sc2 = valid ? s : Slen - 1;
  const uint16_t* src = proj + ((size_t)sc2 * 8 + b) * 384 + 256 + cg;
#pragma unroll
  for (int i = 0; i < 4; ++i) {
    bf16x8 v;
    if (valid) v = *(const bf16x8*)(src + i * 8);
    else       v = (bf16x8){0,0,0,0,0,0,0,0};
    *(bf16x8*)(&Vs[sl][cg + i * 8]) = v;
  }
  __syncthreads();
  const int d = t >> 1, hh = t & 1;     // hh = ks2 half (keys 32hh..32hh+31)
  uint32_t wv[16];
#pragma unroll
  for (int i = 0; i < 16; ++i) {
    int K = 32 * hh + 16 * ((i >> 1) & 1) + 4 * ((i >> 2) & 3) + 2 * (i & 1);
    wv[i] = (uint32_t)Vs[K][d] | ((uint32_t)Vs[K + 1][d] << 16);
  }
  uint16_t* dv = Vtb + (((size_t)b * 32 + kt) * 128 + d) * 64 + hh * 32;
#pragma unroll
  for (int i = 0; i < 4; ++i)
    *(uint4*)(dv + i * 8) = *(uint4*)(&wv[i * 4]);
}

// ---------------------------------------------------------------------------
// 4-way split-K flash attention, QBLK=128, 512 thr (8 waves). LDS-staged
// (R10 structure), swapped QK^T, in-register softmax + P repack.
// splits: keys [512*z, min(Slen, 512*(z+1))), tiles = split*8 + kt.
// ---------------------------------------------------------------------------
__global__ __launch_bounds__(512, 4) void attn_split4(
    const uint16_t* __restrict__ proj, const uint16_t* __restrict__ Vtb,
    float* __restrict__ Opart, float* __restrict__ ml, int Slen)
{
  __shared__ __align__(16) uint16_t KsL[64 * 136];     // [key][k], pitch 136
  __shared__ __align__(16) uint16_t VtL[128 * 72];     // [d][k'],  pitch 72

  const int t  = threadIdx.x;
  const int b  = blockIdx.y;
  const int q0 = blockIdx.x * 128;
  const int split = blockIdx.z;
  const int kbeg = split * 512;
  const int kend = min(Slen, kbeg + 512);
  const int w  = t >> 6;           // 0..7
  const int l  = t & 63;
  const int ln = l & 15;
  const int qd = l >> 4;
  const float scl = 0.08838834764831845f;   // 1/sqrt(128)

  const int kkey = t >> 3, kcg = (t & 7) * 16;   // K staging: 64 keys x 128 halves
  const int vd   = t >> 2, vh  = (t & 3) * 16;   // V staging: 128 d x 64 halves

  bf16x8 qf[4];
  {
    int qrow = q0 + w * 16 + ln;
    int qc = qrow < Slen ? qrow : Slen - 1;
    const uint16_t* qp = proj + ((size_t)qc * 8 + b) * 384 + qd * 8;
#pragma unroll
    for (int ks = 0; ks < 4; ++ks) {
      union { bf16x8 v; uint16_t h[8]; uint32_t u[4]; } in, out;
      in.v = *(const bf16x8*)(qp + ks * 32);
#pragma unroll
      for (int j = 0; j < 4; ++j)
        out.u[j] = pk2bf(frombf(in.h[2 * j]) * scl, frombf(in.h[2 * j + 1]) * scl);
      qf[ks] = out.v;
    }
  }

  f32x4 oacc[8];
#pragma unroll
  for (int i = 0; i < 8; ++i) oacc[i] = (f32x4){0.f, 0.f, 0.f, 0.f};
  float mrow = -INFINITY;          // per-lane: q = q0 + w*16 + ln
  float lrow = 0.f;

  const int ntiles = (kend - kbeg + 63) >> 6;

  for (int kt = 0; kt < ntiles; ++kt) {
    const int key0 = kbeg + kt * 64;
    __syncthreads();
    { // stage K tile: 2x 16B copies per thread
      int kg = key0 + kkey;
      int kc = kg < Slen ? kg : Slen - 1;
      const uint16_t* src = proj + ((size_t)kc * 8 + b) * 384 + 128 + kcg;
      uint16_t* dst = KsL + kkey * 136 + kcg;
      *(bf16x8*)(dst)     = *(const bf16x8*)(src);
      *(bf16x8*)(dst + 8) = *(const bf16x8*)(src + 8);
    }
    { // stage Vt tile: 2x 16B copies per thread
      const int tile = split * 8 + kt;
      const uint16_t* src = Vtb + (((size_t)b * 32 + tile) * 128 + vd) * 64 + vh;
      uint16_t* dst = VtL + vd * 72 + vh;
      *(bf16x8*)(dst)     = *(const bf16x8*)(src);
      *(bf16x8*)(dst + 8) = *(const bf16x8*)(src + 8);
    }
    __syncthreads();

    // QK^T swapped: lane holds S[key = nf*16 + qd*4 + r][q = ln]
    float sc[4][4];
    __builtin_amdgcn_s_setprio(1);
#pragma unroll
    for (int nf = 0; nf < 4; ++nf) {
      f32x4 acc = (f32x4){0.f, 0.f, 0.f, 0.f};
#pragma unroll
      for (int ks = 0; ks < 4; ++ks) {
        bf16x8 kf = *(const bf16x8*)(KsL + (size_t)(nf * 16 + ln) * 136 + ks * 32 + qd * 8);
        acc = __builtin_amdgcn_mfma_f32_16x16x32_bf16(kf, qf[ks], acc, 0, 0, 0);
      }
      int keyb = key0 + nf * 16 + qd * 4;
#pragma unroll
      for (int r = 0; r < 4; ++r)
        sc[nf][r] = (keyb + r < kend) ? acc[r] : -1e30f;
    }
    __builtin_amdgcn_s_setprio(0);

    // online softmax: in-lane 16-max + 2 shuffles
    float mx = sc[0][0];
#pragma unroll
    for (int nf = 0; nf < 4; ++nf)
#pragma unroll
      for (int r = 0; r < 4; ++r) mx = fmaxf(mx, sc[nf][r]);
    mx = fmaxf(mx, __shfl_xor(mx, 16));
    mx = fmaxf(mx, __shfl_xor(mx, 32));
    float mNew = fmaxf(mrow, mx);

    float ps = 0.f;
#pragma unroll
    for (int nf = 0; nf < 4; ++nf) {
      float p0 = __expf(sc[nf][0] - mNew);
      float p1 = __expf(sc[nf][1] - mNew);
      float p2 = __expf(sc[nf][2] - mNew);
      float p3 = __expf(sc[nf][3] - mNew);
      sc[nf][0] = p0; sc[nf][1] = p1; sc[nf][2] = p2; sc[nf][3] = p3;
      ps += (p0 + p1) + (p2 + p3);
    }
    ps += __shfl_xor(ps, 16);
    ps += __shfl_xor(ps, 32);

    float alpha = __expf(mrow - mNew);
    mrow = mNew;
    lrow = lrow * alpha + ps;

    // alpha for the lane's OUTPUT rows q' = qd*4 + r
    float alphaR[4];
#pragma unroll
    for (int r = 0; r < 4; ++r)
      alphaR[r] = __shfl(alpha, (l & 48) | (qd * 4 + r));
#pragma unroll
    for (int no = 0; no < 8; ++no) {
#pragma unroll
      for (int r = 0; r < 4; ++r) oacc[no][r] *= alphaR[r];
    }

    // in-register P -> PV A-fragments (order matches vpack permutation)
    union { bf16x8 v; uint32_t u[4]; } pa0, pa1;
#pragma unroll
    for (int i = 0; i < 4; ++i) {
      pa0.u[i] = pk2bf(sc[(i >> 1)][(i & 1) * 2],     sc[(i >> 1)][(i & 1) * 2 + 1]);
      pa1.u[i] = pk2bf(sc[2 + (i >> 1)][(i & 1) * 2], sc[2 + (i >> 1)][(i & 1) * 2 + 1]);
    }
    __builtin_amdgcn_s_setprio(1);
#pragma unroll
    for (int no = 0; no < 8; ++no) {
      bf16x8 vf = *(const bf16x8*)(VtL + (size_t)(no * 16 + ln) * 72 + qd * 8);
      oacc[no] = __builtin_amdgcn_mfma_f32_16x16x32_bf16(pa0.v, vf, oacc[no], 0, 0, 0);
    }
#pragma unroll
    for (int no = 0; no < 8; ++no) {
      bf16x8 vf = *(const bf16x8*)(VtL + (size_t)(no * 16 + ln) * 72 + 32 + qd * 8);
      oacc[no] = __builtin_amdgcn_mfma_f32_16x16x32_bf16(pa1.v, vf, oacc[no], 0, 0, 0);
    }
    __builtin_amdgcn_s_setprio(0);
  }

  // store unnormalized partials + (m, l)
#pragma unroll
  for (int r = 0; r < 4; ++r) {
    int qg = q0 + w * 16 + qd * 4 + r;
    if (qg < Slen) {
      size_t row = (size_t)qg * 8 + b;
      float* dst = Opart + ((size_t)split * 16384 + row) * 128 + ln;
#pragma unroll
      for (int no = 0; no < 8; ++no) dst[no * 16] = oacc[no][r];
    }
  }
  {
    int qg = q0 + w * 16 + ln;
    if (qd == 0 && qg < Slen) {
      size_t row = (size_t)qg * 8 + b;
      ml[((size_t)split * 16384 + row) * 2 + 0] = mrow;
      ml[((size_t)split * 16384 + row) * 2 + 1] = lrow;
    }
  }
}

// ---------------------------------------------------------------------------
// Out-proj GEMM with INLINE 4-split combine A-staging, raw-barrier async.
// ---------------------------------------------------------------------------
template<bool HEAD>
__global__ __launch_bounds__(256) void gemm_attc64(
    const float* __restrict__ Opart, const float* __restrict__ ml,
    const uint16_t* __restrict__ Wb,
    const float* __restrict__ bias,
    const float* __restrict__ bpW, const float* __restrict__ bpb,
    float* __restrict__ out, int M)
{
  __shared__ __align__(16) uint16_t As[64 * 72];
  __shared__ __align__(16) uint16_t Ws[128 * 72];
  __shared__ float RW[64][5];                 // w0..w3, inv per row
  __shared__ float Ct[HEAD ? 64 : 1][133];

  const int K = 128;
  const int t  = threadIdx.x;
  const int m0 = blockIdx.x * 64;
  const int w  = t >> 6, l = t & 63;
  const int ln = l & 15, qd = l >> 4;

  if (t < 64) {
    int m = m0 + t;
    int mc = m < M ? m : M - 1;
    float mv[4], lv[4];
#pragma unroll
    for (int s = 0; s < 4; ++s) {
      mv[s] = ml[((size_t)s * 16384 + mc) * 2];
      lv[s] = ml[((size_t)s * 16384 + mc) * 2 + 1];
    }
    float Mx = fmaxf(fmaxf(mv[0], mv[1]), fmaxf(mv[2], mv[3]));
    float den = 0.f;
#pragma unroll
    for (int s = 0; s < 4; ++s) {
      float ws = __expf(mv[s] - Mx);
      RW[t][s] = ws;
      den += lv[s] * ws;
    }
    RW[t][4] = 1.f / den;
  }
  __syncthreads();      // RW visible before first (pre-barrier) A-staging

  f32x4 acc[4][2];
#pragma unroll
  for (int i = 0; i < 4; ++i) { acc[i][0] = (f32x4){0,0,0,0}; acc[i][1] = (f32x4){0,0,0,0}; }

  const int rr = t >> 4;
  const int cl = (t & 15) * 4;
  const int r8 = t >> 3;
  const int c8 = (t & 7) * 8;

  float4 ra[4], rc[4], re[4], rg[4];
  bf16x8 wreg[4];

  auto loadA = [&](int k0) {
#pragma unroll
    for (int i = 0; i < 4; ++i) {
      int m = m0 + rr + 16 * i;
      int mc = m < M ? m : M - 1;
      int kk = k0 + cl;
      ra[i] = *(const float4*)(Opart + (size_t)mc * 128 + kk);
      rc[i] = *(const float4*)(Opart + ((size_t)16384 + mc) * 128 + kk);
      re[i] = *(const float4*)(Opart + ((size_t)32768 + mc) * 128 + kk);
      rg[i] = *(const float4*)(Opart + ((size_t)49152 + mc) * 128 + kk);
    }
#pragma unroll
    for (int i = 0; i < 4; ++i) {
      int n = r8 + 32 * i;
      wreg[i] = *(const bf16x8*)(Wb + (size_t)n * K + k0 + c8);
    }
  };

  loadA(0);
  for (int k0 = 0; k0 < K; k0 += 64) {
    WAIT_VM0();
#pragma unroll
    for (int i = 0; i < 4; ++i) {
      int rl = rr + 16 * i;
      float w0 = RW[rl][0], w1 = RW[rl][1], w2 = RW[rl][2], w3 = RW[rl][3];
      float inv = RW[rl][4];
      float4 f = make_float4(
          (ra[i].x * w0 + rc[i].x * w1 + re[i].x * w2 + rg[i].x * w3) * inv,
          (ra[i].y * w0 + rc[i].y * w1 + re[i].y * w2 + rg[i].y * w3) * inv,
          (ra[i].z * w0 + rc[i].z * w1 + re[i].z * w2 + rg[i].z * w3) * inv,
          (ra[i].w * w0 + rc[i].w * w1 + re[i].w * w2 + rg[i].w * w3) * inv);
      *(uint2*)(As + (size_t)rl * 72 + cl) = cvt4(f);
    }
#pragma unroll
    for (int i = 0; i < 4; ++i)
      *(bf16x8*)(Ws + (size_t)(r8 + 32 * i) * 72 + c8) = wreg[i];
    WAIT_LGKM0();
    RAW_BARRIER();
    if (k0 + 64 < K) loadA(k0 + 64);
#pragma unroll
    for (int ks = 0; ks < 2; ++ks) {
      bf16x8 af[4], bfr[2];
#pragma unroll
      for (int mf = 0; mf < 4; ++mf)
        af[mf] = *(const bf16x8*)(As + (size_t)(mf * 16 + ln) * 72 + ks * 32 + qd * 8);
#pragma unroll
      for (int nf = 0; nf < 2; ++nf)
        bfr[nf] = *(const bf16x8*)(Ws + (size_t)(w * 32 + nf * 16 + ln) * 72 + ks * 32 + qd * 8);
#pragma unroll
      for (int mf = 0; mf < 4; ++mf)
#pragma unroll
        for (int nf = 0; nf < 2; ++nf)
          acc[mf][nf] = __builtin_amdgcn_mfma_f32_16x16x32_bf16(af[mf], bfr[nf], acc[mf][nf], 0, 0, 0);
    }
    RAW_BARRIER();
  }

  if (HEAD) {
    __syncthreads();
#pragma unroll
    for (int mf = 0; mf < 4; ++mf) {
#pragma unroll
      for (int r = 0; r < 4; ++r) {
        int rowL = mf * 16 + qd * 4 + r;
#pragma unroll
        for (int nf = 0; nf < 2; ++nf) {
          int n = w * 32 + nf * 16 + ln;
          Ct[rowL][n] = acc[mf][nf][r] + bias[n];
        }
      }
    }
    __syncthreads();
    int row = t >> 2, qg = t & 3;
    int m = m0 + row;
    float p = 0.f;
#pragma unroll
    for (int j = 0; j < 32; ++j) {
      int c = qg + j * 4;
      p += Ct[row][c] * bpW[c];
    }
    p += __shfl_xor(p, 1);
    p += __shfl_xor(p, 2);
    if (qg == 0 && m < M)
      out[m] = 1.f / (1.f + __expf(-(p + bpb[0])));
  } else {
#pragma unroll
    for (int mf = 0; mf < 4; ++mf) {
#pragma unroll
      for (int r = 0; r < 4; ++r) {
        int m = m0 + mf * 16 + qd * 4 + r;
        if (m < M) {
#pragma unroll
          for (int nf = 0; nf < 2; ++nf) {
            int n = w * 32 + nf * 16 + ln;
            out[(size_t)m * 128 + n] = acc[mf][nf][r] + bias[n];
          }
        }
      }
    }
  }
}

// ---------------------------------------------------------------------------
// Cumsum over s of e (S,B,128): 64 chunks x 32 rows (512 blocks p1).
// ---------------------------------------------------------------------------
__global__ void cumsum_p1(const float* __restrict__ e, float* __restrict__ csum,
                          float* __restrict__ part)
{
  int chunk = blockIdx.x, b = blockIdx.y, d = threadIdx.x;
  float run = 0.f;
  int s0 = chunk * 32;
  for (int s = 0; s < 32; ++s) {
    size_t idx = ((size_t)(s0 + s) * 8 + b) * 128 + d;
    run += e[idx];
    csum[idx] = run;
  }
  part[(b * 64 + chunk) * 128 + d] = run;
}

__global__ void cumsum_p2(float* __restrict__ part)
{
  int b = blockIdx.x, d = threadIdx.x;
  float run = 0.f;
  for (int c = 0; c < 64; ++c) {
    float v = part[(b * 64 + c) * 128 + d];
    part[(b * 64 + c) * 128 + d] = run;
    run += v;
  }
}

// ---------------------------------------------------------------------------
extern "C" void kernel_launch(void* const* d_in, const int* in_sizes, int n_in,
                              void* d_out, int out_size, void* d_ws, size_t ws_size,
                              hipStream_t stream)
{
  const float* x       = (const float*)d_in[0];
  const float* pW      = (const float*)d_in[1];
  const float* pb      = (const float*)d_in[2];
  const float* cW      = (const float*)d_in[3];
  const float* cb      = (const float*)d_in[4];
  const float* aW      = (const float*)d_in[5];
  const float* ab      = (const float*)d_in[6];
  const float* uW      = (const float*)d_in[7];
  const float* ub      = (const float*)d_in[8];
  const float* eW      = (const float*)d_in[9];
  const float* eb      = (const float*)d_in[10];
  const float* la_win  = (const float*)d_in[11];
  const float* la_bin  = (const float*)d_in[12];
  const float* la_wout = (const float*)d_in[13];
  const float* la_bout = (const float*)d_in[14];
  const float* beW     = (const float*)d_in[15];
  const float* beb     = (const float*)d_in[16];
  const float* ba_win  = (const float*)d_in[17];
  const float* ba_bin  = (const float*)d_in[18];
  const float* ba_wout = (const float*)d_in[19];
  const float* ba_bout = (const float*)d_in[20];
  const float* bpW     = (const float*)d_in[21];
  const float* bpb     = (const float*)d_in[22];

  float* ws   = (float*)d_ws;
  float* outF = (float*)d_out;

  // Workspace (float offsets):
  //  [0, 344064)                  WB bf16 weights
  //  M0=344064:
  //  [M0, +4,194,304)             feats bf16 / csum fp32
  //  [M0+2,097,152, +65,536)      partB (coexists only with csum)
  //  [M0+4,194,304, +1,048,576)   e0 / b0 bf16 (serial)
  //  [M0+5,242,880, +3,145,728)   proj bf16
  //  [M0+8,388,608, +1,048,576)   Vtb bf16
  //  [M0+9,437,184, +8,388,608)   Opart fp32 (4 splits)
  //  [M0+17,825,792, +131,072)    ml (4 splits)
  uint16_t* WB  = (uint16_t*)ws;
  float* base   = ws + 344064;
  uint16_t* featsB = (uint16_t*)base;
  float* csumB  = base;
  float* partB  = base + 2097152;
  uint16_t* eB  = (uint16_t*)(base + 4194304);   // e0 / b0
  uint16_t* projB = (uint16_t*)(base + 5242880);
  uint16_t* VtbB  = (uint16_t*)(base + 8388608);
  float* OpartB = base + 9437184;
  float* mlB    = base + 17825792;

  // 0. weights -> bf16
  WPtrs wp;
  wp.p[0] = pW; wp.p[1] = cW; wp.p[2] = aW; wp.p[3] = uW; wp.p[4] = eW;
  wp.p[5] = la_win; wp.p[6] = la_wout; wp.p[7] = beW; wp.p[8] = ba_win; wp.p[9] = ba_wout;
  pack_weights<<<dim3(672), 256, 0, stream>>>(wp, WB);

  // 1. feats = relu(segment linears) -> bf16
  gemm_feats64<<<dim3(256, 4), 256, 0, stream>>>(x, WB, pb, cb, ab, ub, featsB);
  // 2. e0 = relu(feats @ eW^T + eb) -> bf16, remapped (B,S)->(S,B)
  gemm64<true, true, true, true><<<dim3(256, 1), 256, 0, stream>>>(
      featsB, 512, WB + OFF_EW, eb, eB, 128, 16384, 512);
  // 3. proj1 = e0 @ la_win^T + la_bin -> bf16
  gemm64<true, true, false, false><<<dim3(256, 3), 256, 0, stream>>>(
      eB, 128, WB + OFF_LAWIN, la_bin, projB, 384, 16384, 128);
  // 4. V pack + 4-split flash (QBLK=128, 512 thr)
  vpack<<<dim3(32, 8), 256, 0, stream>>>(projB, VtbB, 2048);
  attn_split4<<<dim3(16, 8, 4), 512, 0, stream>>>(projB, VtbB, OpartB, mlB, 2048);
  // 5. e = combine(att1) @ la_wout^T + la_bout -> d_out (fp32), combine inlined
  gemm_attc64<false><<<dim3(256), 256, 0, stream>>>(
      OpartB, mlB, WB + OFF_LAWOUT, la_bout, nullptr, nullptr, outF, 16384);
  // 6-7. csum (local prefixes + chunk offsets; p3 fused into becat)
  cumsum_p1<<<dim3(64, 8), 128, 0, stream>>>(outF, csumB, partB);
  cumsum_p2<<<dim3(8), 128, 0, stream>>>(partB);
  // 8. b0 = relu(cat(left,right) @ beW^T + beb) -> bf16
  gemm_becat64<<<dim3(256), 256, 0, stream>>>(csumB, partB, WB + OFF_BEW, beb, eB);
  // 9. proj2
  gemm64<true, true, false, false><<<dim3(256, 3), 256, 0, stream>>>(
      eB, 128, WB + OFF_BAWIN, ba_bin, projB, 384, 16376, 128);
  // 10. V pack + att2 (Slen = 2047)
  vpack<<<dim3(32, 8), 256, 0, stream>>>(projB, VtbB, 2047);
  attn_split4<<<dim3(16, 8, 4), 512, 0, stream>>>(projB, VtbB, OpartB, mlB, 2047);
  // 11. bout GEMM: combine inlined + fused sigmoid head -> d_out tail
  gemm_attc64<true><<<dim3(256), 256, 0, stream>>>(
      OpartB, mlB, WB + OFF_BAWOUT, ba_bout, bpW, bpb, outF + 2097152, 16376);
}